// Round 15
// baseline (535.195 us; speedup 1.0000x reference)
//
#include <hip/hip_runtime.h>
#include <cstdint>
#include <cstddef>

#define N_NODES 50000
#define M_PAD 50048    // 391 * 128, covers GEMM tile over-read
#define E_EDGES 800000
#define INCH 128
#define HID 64
#define HEADS 4
#define NHD 256      // HEADS*HID
#define NGRAPH 64
#define DCAT 640     // 128 + 256 + 256
#define NEG_SLOPE 0.2f

typedef __attribute__((ext_vector_type(8))) short bf16x8;
typedef __attribute__((ext_vector_type(4))) float f32x4;

// round-to-nearest-even fp32 -> bf16 bits
static __device__ inline unsigned short f2bf(float f) {
    unsigned int u = __float_as_uint(f);
    unsigned int r = (u + 0x7FFFu + ((u >> 16) & 1u)) >> 16;
    return (unsigned short)r;
}
static __device__ inline float bf2f(unsigned short b) {
    return __uint_as_float(((unsigned int)b) << 16);
}

// ---- fused preamble: hist + goff + psums-zero + splits + W*a projections ----
#define W1N (INCH * NHD)            // 32768
#define W2N (NHD * NHD)             // 65536
#define XN  (N_NODES * INCH)        // 6.4M
#define HB  ((E_EDGES + 255) / 256)           // 3125
#define GB  ((N_NODES + 255) / 256)           // 196
#define PZB ((NGRAPH * DCAT + 255) / 256)     // 160
#define SPB ((W1N + W2N + XN + 255) / 256)    // splits
#define WAB ((INCH * 8 + NHD * 8 + 255) / 256)  // 12: W1a[128][8], W2a[256][8]
#define PREPB (HB + GB + PZB + SPB + WAB)

__global__ void prep_kernel(
    const int* __restrict__ ei, const int* __restrict__ batch,
    const float* __restrict__ W1, const float* __restrict__ W2,
    const float* __restrict__ x,
    const float* __restrict__ a1s, const float* __restrict__ a1d,
    const float* __restrict__ a2s, const float* __restrict__ a2d,
    int* __restrict__ counts, int* __restrict__ goff,
    float* __restrict__ psums,
    unsigned short* __restrict__ w1thi, unsigned short* __restrict__ w1tlo,
    unsigned short* __restrict__ w2thi, unsigned short* __restrict__ w2tlo,
    unsigned short* __restrict__ xb,
    float* __restrict__ W1a, float* __restrict__ W2a)
{
    const int b = blockIdx.x;
    if (b < HB) {                               // ---- histogram of dst ----
        const int e = b * 256 + threadIdx.x;
        if (e < E_EDGES) atomicAdd(&counts[ei[E_EDGES + e]], 1);
        return;
    }
    if (b < HB + GB) {                          // ---- graph offsets ----
        const int n = (b - HB) * 256 + threadIdx.x;
        if (n >= N_NODES) return;
        const int bb = batch[n];
        const int bp = (n == 0) ? -1 : batch[n - 1];
        for (int g = bp + 1; g <= bb; ++g) goff[g] = n;
        if (n == N_NODES - 1)
            for (int g = bb + 1; g <= NGRAPH; ++g) goff[g] = N_NODES;
        return;
    }
    if (b < HB + GB + PZB) {                    // ---- zero psums ----
        const int i = (b - HB - GB) * 256 + threadIdx.x;
        if (i < NGRAPH * DCAT) psums[i] = 0.f;
        return;
    }
    if (b < HB + GB + PZB + SPB) {              // ---- splits ----
        const int i = (b - HB - GB - PZB) * 256 + threadIdx.x;
        if (i < W1N) {
            const int n = i / INCH, k = i - n * INCH;
            const float v = W1[(size_t)k * NHD + n];
            const unsigned short h = f2bf(v);
            w1thi[i] = h; w1tlo[i] = f2bf(v - bf2f(h));
        } else if (i < W1N + W2N) {
            const int j = i - W1N;
            const int n = j / NHD, k = j - n * NHD;
            const float v = W2[(size_t)k * NHD + n];
            const unsigned short h = f2bf(v);
            w2thi[j] = h; w2tlo[j] = f2bf(v - bf2f(h));
        } else {
            const int j = i - W1N - W2N;
            if (j < XN) xb[j] = f2bf(x[j]);
        }
        return;
    }
    // ---- W*a projections: W1a[k][j] = sum_d W1[k, h*64+d]*a[h][d] ----
    const int i = (b - HB - GB - PZB - SPB) * 256 + threadIdx.x;
    if (i < INCH * 8) {
        const int k = i >> 3, j = i & 7, h = j & 3;
        const float* a = (j < 4) ? a1s : a1d;
        float s = 0.f;
        for (int d = 0; d < HID; ++d)
            s += W1[(size_t)k * NHD + h * HID + d] * a[h * HID + d];
        W1a[i] = s;
    } else if (i < INCH * 8 + NHD * 8) {
        const int i2 = i - INCH * 8;
        const int k = i2 >> 3, j = i2 & 7, h = j & 3;
        const float* a = (j < 4) ? a2s : a2d;
        float s = 0.f;
        for (int d = 0; d < HID; ++d)
            s += W2[(size_t)k * NHD + h * HID + d] * a[h * HID + d];
        W2a[i2] = s;
    }
}

// ---- es1: es/ed[n,h] = x[n,:] @ W1a[:, h] (wave per node, grid-stride) -----
__global__ __launch_bounds__(256) void es1_kernel(
    const float* __restrict__ x, const float* __restrict__ W1a,
    float* __restrict__ es, float* __restrict__ ed)
{
    const int wid = threadIdx.x >> 6, lane = threadIdx.x & 63;
    float wa[2][8];
#pragma unroll
    for (int r = 0; r < 2; ++r)
#pragma unroll
        for (int j = 0; j < 8; j += 4)
            *(float4*)&wa[r][j] = *(const float4*)(W1a + (size_t)(lane * 2 + r) * 8 + j);
    for (int node = blockIdx.x * 4 + wid; node < N_NODES; node += gridDim.x * 4) {
        const float2 xv = *(const float2*)(x + (size_t)node * INCH + lane * 2);
        float p[8];
#pragma unroll
        for (int j = 0; j < 8; ++j) p[j] = xv.x * wa[0][j] + xv.y * wa[1][j];
#pragma unroll
        for (int off = 1; off < 64; off <<= 1)
#pragma unroll
            for (int j = 0; j < 8; ++j) p[j] += __shfl_xor(p[j], off, 64);
        if (lane < 4)       es[node * 4 + lane]     = p[lane];
        else if (lane < 8)  ed[node * 4 + lane - 4] = p[lane];
    }
}

// ---- es2: from bf16 h1 (256 cols) ------------------------------------------
__global__ __launch_bounds__(256) void es2_kernel(
    const unsigned short* __restrict__ h1b, const float* __restrict__ W2a,
    float* __restrict__ es, float* __restrict__ ed)
{
    const int wid = threadIdx.x >> 6, lane = threadIdx.x & 63;
    float wa[4][8];
#pragma unroll
    for (int r = 0; r < 4; ++r)
#pragma unroll
        for (int j = 0; j < 8; j += 4)
            *(float4*)&wa[r][j] = *(const float4*)(W2a + (size_t)(lane * 4 + r) * 8 + j);
    for (int node = blockIdx.x * 4 + wid; node < N_NODES; node += gridDim.x * 4) {
        const ushort4 hv = *(const ushort4*)(h1b + (size_t)node * NHD + lane * 4);
        const float h0 = bf2f(hv.x), h1 = bf2f(hv.y), h2 = bf2f(hv.z), h3 = bf2f(hv.w);
        float p[8];
#pragma unroll
        for (int j = 0; j < 8; ++j)
            p[j] = h0 * wa[0][j] + h1 * wa[1][j] + h2 * wa[2][j] + h3 * wa[3][j];
#pragma unroll
        for (int off = 1; off < 64; off <<= 1)
#pragma unroll
            for (int j = 0; j < 8; ++j) p[j] += __shfl_xor(p[j], off, 64);
        if (lane < 4)       es[node * 4 + lane]     = p[lane];
        else if (lane < 8)  ed[node * 4 + lane - 4] = p[lane];
    }
}

// ------------------------------ CSR scan ------------------------------------
#define SBLK 1024
#define NSCB ((N_NODES + SBLK - 1) / SBLK)   // 49

__global__ __launch_bounds__(1024) void scan_local_kernel(
    const int* __restrict__ counts, int* __restrict__ offsets,
    int* __restrict__ bsum)
{
    __shared__ int tmp[SBLK];
    const int t = threadIdx.x;
    const int i = blockIdx.x * SBLK + t;
    const int v = (i < N_NODES) ? counts[i] : 0;
    tmp[t] = v;
    __syncthreads();
    for (int off = 1; off < SBLK; off <<= 1) {
        const int u = (t >= off) ? tmp[t - off] : 0;
        __syncthreads();
        tmp[t] += u;
        __syncthreads();
    }
    if (i < N_NODES) offsets[i] = tmp[t] - v;
    if (t == SBLK - 1) bsum[blockIdx.x] = tmp[t];
}

__global__ __launch_bounds__(1024) void scan_final_kernel(
    int* __restrict__ offsets, int* __restrict__ cursor,
    const int* __restrict__ bsum)
{
    __shared__ int base_sh;
    const int b = blockIdx.x;
    if (threadIdx.x == 0) {
        int s = 0;
        for (int j = 0; j < b; ++j) s += bsum[j];
        base_sh = s;
    }
    __syncthreads();
    const int i = b * SBLK + threadIdx.x;
    if (i < N_NODES) {
        const int v = offsets[i] + base_sh;
        offsets[i] = v;
        cursor[i]  = v;
    }
    if (b == 0 && threadIdx.x == 0) offsets[N_NODES] = E_EDGES;
}

__global__ void scatter_kernel(const int* __restrict__ ei, int* __restrict__ cursor,
                               int* __restrict__ csr)
{
    const int e = blockIdx.x * 256 + threadIdx.x;
    if (e >= E_EDGES) return;
    const int s = ei[e];
    const int d = ei[E_EDGES + e];
    const int pos = atomicAdd(&cursor[d], 1);
    csr[pos] = s;
}

// ---- aggregate1: gather bf16 x rows (256B), 4-head weighted sums ------------
// out xab[n][h][128] bf16, normalized by per-head softmax denom.
__global__ __launch_bounds__(256) void aggregate1_kernel(
    const unsigned short* __restrict__ xb, const int* __restrict__ csr,
    const int* __restrict__ offsets,
    const float* __restrict__ es, const float* __restrict__ ed,
    unsigned short* __restrict__ xab)
{
    const int wid  = threadIdx.x >> 6;
    const int lane = threadIdx.x & 63;
    const int node = blockIdx.x * 4 + wid;
    if (node >= N_NODES) return;
    const int col = lane * 2;            // 2 cols per lane (128 total)
    const int sub = lane & 15;

    const float4 edv = *(const float4*)(ed + node * 4);
    const int beg = offsets[node], end = offsets[node + 1];

    float acc[4][2] = {};
    float ds[4] = {0.f, 0.f, 0.f, 0.f};

    int base = beg;
    int m_cur = min(16, end - base);
    int s_cur = 0; float4 w_cur = make_float4(0.f, 0.f, 0.f, 0.f);
    if (base < end && sub < m_cur) {
        s_cur = csr[base + sub];
        const float4 e4 = *(const float4*)(es + s_cur * 4);
        float u0 = e4.x + edv.x, u1 = e4.y + edv.y;
        float u2 = e4.z + edv.z, u3 = e4.w + edv.w;
        u0 = u0 > 0.f ? u0 : NEG_SLOPE * u0;
        u1 = u1 > 0.f ? u1 : NEG_SLOPE * u1;
        u2 = u2 > 0.f ? u2 : NEG_SLOPE * u2;
        u3 = u3 > 0.f ? u3 : NEG_SLOPE * u3;
        w_cur = make_float4(expf(u0), expf(u1), expf(u2), expf(u3));
    }

    while (base < end) {
        const int base_n = base + 16;
        const int m_nxt = min(16, end - base_n);
        int s_nxt = 0; float4 w_nxt = make_float4(0.f, 0.f, 0.f, 0.f);
        if (base_n < end && sub < m_nxt) {
            s_nxt = csr[base_n + sub];
            const float4 e4 = *(const float4*)(es + s_nxt * 4);
            float u0 = e4.x + edv.x, u1 = e4.y + edv.y;
            float u2 = e4.z + edv.z, u3 = e4.w + edv.w;
            u0 = u0 > 0.f ? u0 : NEG_SLOPE * u0;
            u1 = u1 > 0.f ? u1 : NEG_SLOPE * u1;
            u2 = u2 > 0.f ? u2 : NEG_SLOPE * u2;
            u3 = u3 > 0.f ? u3 : NEG_SLOPE * u3;
            w_nxt = make_float4(expf(u0), expf(u1), expf(u2), expf(u3));
        }
        if (m_cur == 16) {
#pragma unroll
            for (int i = 0; i < 16; ++i) {
                const int   s  = (int)__builtin_amdgcn_readlane((unsigned)s_cur, i);
                const float wx = __shfl(w_cur.x, i, 64);
                const float wy = __shfl(w_cur.y, i, 64);
                const float wz = __shfl(w_cur.z, i, 64);
                const float ww = __shfl(w_cur.w, i, 64);
                const unsigned int xv = *(const unsigned int*)(xb + (size_t)s * INCH + col);
                const float x0 = bf2f((unsigned short)(xv & 0xFFFF));
                const float x1 = bf2f((unsigned short)(xv >> 16));
                acc[0][0] += wx * x0; acc[0][1] += wx * x1;
                acc[1][0] += wy * x0; acc[1][1] += wy * x1;
                acc[2][0] += wz * x0; acc[2][1] += wz * x1;
                acc[3][0] += ww * x0; acc[3][1] += ww * x1;
                ds[0] += wx; ds[1] += wy; ds[2] += wz; ds[3] += ww;
            }
        } else {
            for (int i = 0; i < m_cur; ++i) {
                const int   s  = __shfl(s_cur, i, 64);
                const float wx = __shfl(w_cur.x, i, 64);
                const float wy = __shfl(w_cur.y, i, 64);
                const float wz = __shfl(w_cur.z, i, 64);
                const float ww = __shfl(w_cur.w, i, 64);
                const unsigned int xv = *(const unsigned int*)(xb + (size_t)s * INCH + col);
                const float x0 = bf2f((unsigned short)(xv & 0xFFFF));
                const float x1 = bf2f((unsigned short)(xv >> 16));
                acc[0][0] += wx * x0; acc[0][1] += wx * x1;
                acc[1][0] += wy * x0; acc[1][1] += wy * x1;
                acc[2][0] += wz * x0; acc[2][1] += wz * x1;
                acc[3][0] += ww * x0; acc[3][1] += ww * x1;
                ds[0] += wx; ds[1] += wy; ds[2] += wz; ds[3] += ww;
            }
        }
        s_cur = s_nxt; w_cur = w_nxt; m_cur = m_nxt; base = base_n;
    }

#pragma unroll
    for (int h = 0; h < 4; ++h) {
        const float inv = 1.0f / (ds[h] + 1e-16f);
        unsigned int o = (unsigned int)f2bf(acc[h][0] * inv)
                       | ((unsigned int)f2bf(acc[h][1] * inv) << 16);
        *(unsigned int*)(xab + ((size_t)node * 4 + h) * INCH + col) = o;
    }
}

// ---- gemm_h1: h1[:, h*64:(h+1)*64] = relu(xab[:,h,:] @ W1[:,h-cols] + b1) ---
// grid (391, 4); tile 128 rows x 64 cols, K=128; A bf16, B hi+lo (2-pass).
#define GK 32
#define LDA 40

__global__ __launch_bounds__(256) void gemm_h1_kernel(
    const unsigned short* __restrict__ xab,
    const unsigned short* __restrict__ Bthi,
    const unsigned short* __restrict__ Btlo,
    const float* __restrict__ b1,
    unsigned short* __restrict__ h1b, int M)
{
    __shared__ unsigned short Ash[128 * LDA];
    __shared__ unsigned short Bh[64 * LDA];
    __shared__ unsigned short Bl[64 * LDA];

    const int head = blockIdx.y;
    const int row0 = blockIdx.x * 128;
    const int t = threadIdx.x, wave = t >> 6, lane = t & 63;
    const int m16 = lane & 15, quad = lane >> 4;
    const int wr = wave * 32;

    f32x4 acc[2][4];
#pragma unroll
    for (int i = 0; i < 2; ++i)
#pragma unroll
        for (int j = 0; j < 4; ++j) acc[i][j] = (f32x4){0.f, 0.f, 0.f, 0.f};

    for (int k0 = 0; k0 < INCH; k0 += GK) {
#pragma unroll
        for (int i = 0; i < 2; ++i) {
            const int seg = t + i * 256;          // 512 segs of 8 bf16
            const int r = seg >> 2, p = (seg & 3) * 8;
            *(int4*)(&Ash[r * LDA + p]) =
                *(const int4*)(xab + ((size_t)(row0 + r) * 4 + head) * INCH + k0 + p);
        }
        {
            const int r = t >> 2, p = (t & 3) * 8; // 256 segs: 64 rows
            const size_t gb = (size_t)(head * 64 + r) * INCH + k0 + p;
            *(int4*)(&Bh[r * LDA + p]) = *(const int4*)(Bthi + gb);
            *(int4*)(&Bl[r * LDA + p]) = *(const int4*)(Btlo + gb);
        }
        __syncthreads();

        bf16x8 af[2];
#pragma unroll
        for (int i = 0; i < 2; ++i)
            af[i] = *(const bf16x8*)(&Ash[(wr + i * 16 + m16) * LDA + quad * 8]);
#pragma unroll
        for (int j = 0; j < 4; ++j) {
            const int n = j * 16 + m16;
            const bf16x8 bh = *(const bf16x8*)(&Bh[n * LDA + quad * 8]);
            const bf16x8 bl = *(const bf16x8*)(&Bl[n * LDA + quad * 8]);
#pragma unroll
            for (int i = 0; i < 2; ++i) {
                acc[i][j] = __builtin_amdgcn_mfma_f32_16x16x32_bf16(af[i], bh, acc[i][j], 0, 0, 0);
                acc[i][j] = __builtin_amdgcn_mfma_f32_16x16x32_bf16(af[i], bl, acc[i][j], 0, 0, 0);
            }
        }
        __syncthreads();
    }

#pragma unroll
    for (int i = 0; i < 2; ++i)
#pragma unroll
        for (int reg = 0; reg < 4; ++reg) {
            const int r = row0 + wr + i * 16 + quad * 4 + reg;
            if (r < M) {
#pragma unroll
                for (int j = 0; j < 4; ++j) {
                    const int c = head * 64 + j * 16 + m16;
                    h1b[(size_t)r * NHD + c] = f2bf(fmaxf(acc[i][j][reg] + b1[c], 0.f));
                }
            }
        }
}

// ---- aggregate2: v3 gather of h1 rows (512B), normalized, no bias/relu -----
__global__ __launch_bounds__(256) void aggregate2_kernel(
    const unsigned short* __restrict__ hb, const int* __restrict__ csr,
    const int* __restrict__ offsets,
    const float* __restrict__ es, const float* __restrict__ ed,
    unsigned short* __restrict__ outb)
{
    const int wid  = threadIdx.x >> 6;
    const int lane = threadIdx.x & 63;
    const int node = blockIdx.x * 4 + wid;
    if (node >= N_NODES) return;
    const int head = lane >> 4;
    const int col  = lane * 4;
    const int sub  = lane & 15;

    const float edc = ed[node * 4 + head];
    const int beg = offsets[node], end = offsets[node + 1];

    float4 acc = make_float4(0.f, 0.f, 0.f, 0.f);
    float dsum = 0.f;

    int base = beg;
    int m_cur = min(16, end - base);
    int s_cur = 0; float w_cur = 0.f;
    if (base < end && sub < m_cur) {
        s_cur = csr[base + sub];
        float u = es[s_cur * 4 + head] + edc;
        u = u > 0.f ? u : NEG_SLOPE * u;
        w_cur = expf(u);
    }

    while (base < end) {
        const int base_n = base + 16;
        const int m_nxt = min(16, end - base_n);
        int s_nxt = 0; float w_nxt = 0.f;
        if (base_n < end && sub < m_nxt) {
            s_nxt = csr[base_n + sub];
            float u = es[s_nxt * 4 + head] + edc;
            u = u > 0.f ? u : NEG_SLOPE * u;
            w_nxt = expf(u);
        }
        if (m_cur == 16) {
#pragma unroll
            for (int i = 0; i < 16; ++i) {
                const int   s = (int)__builtin_amdgcn_readlane((unsigned)s_cur, i);
                const float w = __shfl(w_cur, (lane & 48) + i, 64);
                const ushort4 v = *(const ushort4*)(hb + (size_t)s * NHD + col);
                acc.x += w * bf2f(v.x);
                acc.y += w * bf2f(v.y);
                acc.z += w * bf2f(v.z);
                acc.w += w * bf2f(v.w);
                dsum += w;
            }
        } else {
            for (int i = 0; i < m_cur; ++i) {
                const int   s = __shfl(s_cur, i, 64);
                const float w = __shfl(w_cur, (lane & 48) + i, 64);
                const ushort4 v = *(const ushort4*)(hb + (size_t)s * NHD + col);
                acc.x += w * bf2f(v.x);
                acc.y += w * bf2f(v.y);
                acc.z += w * bf2f(v.z);
                acc.w += w * bf2f(v.w);
                dsum += w;
            }
        }
        s_cur = s_nxt; w_cur = w_nxt; m_cur = m_nxt; base = base_n;
    }

    const float inv = 1.0f / (dsum + 1e-16f);
    ushort4 oh;
    oh.x = f2bf(acc.x * inv); oh.y = f2bf(acc.y * inv);
    oh.z = f2bf(acc.z * inv); oh.w = f2bf(acc.w * inv);
    *(ushort4*)(outb + (size_t)node * NHD + col) = oh;
}

// ---- gemm_h2: h2 = relu(h1ab @ (W2hi+W2lo) + b2); 128x256 tile, K=256 ------
__global__ __launch_bounds__(256, 2) void gemm_h2_kernel(
    const unsigned short* __restrict__ At,
    const unsigned short* __restrict__ Bthi,
    const unsigned short* __restrict__ Btlo,
    const float* __restrict__ b2,
    unsigned short* __restrict__ h2b, int M)
{
    __shared__ unsigned short Ash[128 * LDA];
    __shared__ unsigned short Bhi[256 * LDA];
    __shared__ unsigned short Blo[256 * LDA];

    const int t    = threadIdx.x;
    const int row0 = blockIdx.x * 128;
    const int wave = t >> 6, lane = t & 63;
    const int wr  = (wave >> 1) * 64;
    const int wc2 = (wave & 1) * 128;
    const int m16 = lane & 15, quad = lane >> 4;

    f32x4 acc[4][8];
#pragma unroll
    for (int i = 0; i < 4; ++i)
#pragma unroll
        for (int j = 0; j < 8; ++j) acc[i][j] = (f32x4){0.f, 0.f, 0.f, 0.f};

    for (int k0 = 0; k0 < NHD; k0 += GK) {
#pragma unroll
        for (int i = 0; i < 2; ++i) {
            const int seg = t + i * 256;
            const int r = seg >> 2, p = (seg & 3) * 8;
            *(int4*)(&Ash[r * LDA + p]) = *(const int4*)(At + (size_t)(row0 + r) * NHD + k0 + p);
        }
#pragma unroll
        for (int i = 0; i < 4; ++i) {
            const int seg = t + i * 256;
            const int r = seg >> 2, p = (seg & 3) * 8;
            const size_t gb = (size_t)r * NHD + k0 + p;
            *(int4*)(&Bhi[r * LDA + p]) = *(const int4*)(Bthi + gb);
            *(int4*)(&Blo[r * LDA + p]) = *(const int4*)(Btlo + gb);
        }
        __syncthreads();

        bf16x8 af[4];
#pragma unroll
        for (int i = 0; i < 4; ++i)
            af[i] = *(const bf16x8*)(&Ash[(wr + i * 16 + m16) * LDA + quad * 8]);
#pragma unroll
        for (int j = 0; j < 8; ++j) {
            const int n = wc2 + j * 16 + m16;
            const bf16x8 bh = *(const bf16x8*)(&Bhi[n * LDA + quad * 8]);
            const bf16x8 bl = *(const bf16x8*)(&Blo[n * LDA + quad * 8]);
#pragma unroll
            for (int i = 0; i < 4; ++i) {
                acc[i][j] = __builtin_amdgcn_mfma_f32_16x16x32_bf16(af[i], bh, acc[i][j], 0, 0, 0);
                acc[i][j] = __builtin_amdgcn_mfma_f32_16x16x32_bf16(af[i], bl, acc[i][j], 0, 0, 0);
            }
        }
        __syncthreads();
    }

#pragma unroll
    for (int i = 0; i < 4; ++i)
#pragma unroll
        for (int reg = 0; reg < 4; ++reg) {
            const int r = row0 + wr + i * 16 + quad * 4 + reg;
            if (r < M) {
#pragma unroll
                for (int j = 0; j < 8; ++j) {
                    const int c = wc2 + j * 16 + m16;
                    h2b[(size_t)r * NHD + c] = f2bf(fmaxf(acc[i][j][reg] + b2[c], 0.f));
                }
            }
        }
}

// ------------------------------ pooling (all-bf16 sources) -------------------
#define PRB 128

__global__ __launch_bounds__(640) void pool_sum_kernel(
    const unsigned short* __restrict__ xb, const unsigned short* __restrict__ h1b,
    const unsigned short* __restrict__ h2b, const int* __restrict__ batch,
    float* __restrict__ sums)
{
    __shared__ int bsh[PRB];
    const int c  = threadIdx.x;
    const int r0 = blockIdx.x * PRB;
    const int r1 = min(N_NODES, r0 + PRB);
    const int nr = r1 - r0;
    if (c < nr) bsh[c] = batch[r0 + c];
    __syncthreads();

    const unsigned short* srcb; int ld, cc;
    if (c < INCH)            { srcb = xb;  ld = INCH; cc = c; }
    else if (c < INCH + NHD) { srcb = h1b; ld = NHD;  cc = c - INCH; }
    else                     { srcb = h2b; ld = NHD;  cc = c - INCH - NHD; }

    float sum = 0.f;
    int g = bsh[0];
    for (int i = 0; i < nr; ++i) {
        const int gb = bsh[i];
        if (gb != g) {
            atomicAdd(&sums[g * DCAT + c], sum);
            sum = 0.f;
            g = gb;
        }
        sum += bf2f(srcb[(size_t)(r0 + i) * ld + cc]);
    }
    atomicAdd(&sums[g * DCAT + c], sum);
}

// --------------- MLP head: one graph per block (64 blocks) -------------------
__global__ __launch_bounds__(256) void mlp_kernel(
    const float* __restrict__ psums, const int* __restrict__ goff,
    const float* __restrict__ W3, const float* __restrict__ b3,
    const float* __restrict__ W4, const float* __restrict__ b4,
    float* __restrict__ out)
{
    const int g = blockIdx.x;
    __shared__ float p[DCAT];
    __shared__ float hm[256];
    const float inv = 1.0f / fmaxf((float)(goff[g + 1] - goff[g]), 1.0f);
    for (int i = threadIdx.x; i < DCAT; i += 256)
        p[i] = psums[(size_t)g * DCAT + i] * inv;
    __syncthreads();
    const int c = threadIdx.x;
    float s = b3[c];
    for (int k = 0; k < DCAT; ++k) s += p[k] * W3[(size_t)k * 256 + c];
    hm[c] = fmaxf(s, 0.f);
    __syncthreads();
    if (c < 128) {
        float o = b4[c];
        for (int k = 0; k < 256; ++k) o += hm[k] * W4[(size_t)k * 128 + c];
        out[(size_t)g * 128 + c] = o;
    }
}

// ------------------------------ launch --------------------------------------
extern "C" void kernel_launch(void* const* d_in, const int* in_sizes, int n_in,
                              void* d_out, int out_size, void* d_ws, size_t ws_size,
                              hipStream_t stream)
{
    const float* x     = (const float*)d_in[0];
    const int*   ei    = (const int*)d_in[1];
    const int*   batch = (const int*)d_in[2];
    const float* W1    = (const float*)d_in[3];
    const float* a1s   = (const float*)d_in[4];
    const float* a1d   = (const float*)d_in[5];
    const float* b1    = (const float*)d_in[6];
    const float* W2    = (const float*)d_in[7];
    const float* a2s   = (const float*)d_in[8];
    const float* a2d   = (const float*)d_in[9];
    const float* b2    = (const float*)d_in[10];
    const float* W3    = (const float*)d_in[11];
    const float* b3    = (const float*)d_in[12];
    const float* W4    = (const float*)d_in[13];
    const float* b4    = (const float*)d_in[14];
    float* out = (float*)d_out;

    size_t off = 0;
    auto carve = [&](size_t bytes) -> void* {
        void* p = (char*)d_ws + off;
        off = (off + bytes + 255) & ~(size_t)255;
        return p;
    };
    unsigned short* xb    = (unsigned short*)carve((size_t)M_PAD * INCH * 2);
    unsigned short* xab   = (unsigned short*)carve((size_t)M_PAD * 4 * INCH * 2);
    unsigned short* h1b   = (unsigned short*)carve((size_t)M_PAD * NHD * 2);
    unsigned short* h1ab  = (unsigned short*)carve((size_t)M_PAD * NHD * 2);
    unsigned short* h2b   = (unsigned short*)carve((size_t)N_NODES * NHD * 2);
    float* es     = (float*)carve((size_t)N_NODES * HEADS * 4);
    float* ed     = (float*)carve((size_t)N_NODES * HEADS * 4);
    float* psums  = (float*)carve((size_t)NGRAPH * DCAT * 4);
    float* W1a    = (float*)carve((size_t)INCH * 8 * 4);
    float* W2a    = (float*)carve((size_t)NHD * 8 * 4);
    int*   counts  = (int*)carve((size_t)N_NODES * 4);
    int*   offsets = (int*)carve((size_t)(N_NODES + 1) * 4);
    int*   cursor  = (int*)carve((size_t)N_NODES * 4);
    int*   csr     = (int*)carve((size_t)E_EDGES * 4);
    int*   goff    = (int*)carve((size_t)(NGRAPH + 1) * 4);
    int*   bsum    = (int*)carve((size_t)NSCB * 4);
    unsigned short* w1thi = (unsigned short*)carve((size_t)NHD * INCH * 2);
    unsigned short* w1tlo = (unsigned short*)carve((size_t)NHD * INCH * 2);
    unsigned short* w2thi = (unsigned short*)carve((size_t)NHD * NHD * 2);
    unsigned short* w2tlo = (unsigned short*)carve((size_t)NHD * NHD * 2);

    const int egrid = (E_EDGES + 255) / 256;

    // ---- preamble ----
    hipMemsetAsync(counts, 0, (size_t)N_NODES * 4, stream);
    prep_kernel<<<PREPB, 256, 0, stream>>>(ei, batch, W1, W2, x,
                                           a1s, a1d, a2s, a2d,
                                           counts, goff, psums,
                                           w1thi, w1tlo, w2thi, w2tlo, xb,
                                           W1a, W2a);
    scan_local_kernel<<<NSCB, SBLK, 0, stream>>>(counts, offsets, bsum);
    scan_final_kernel<<<NSCB, SBLK, 0, stream>>>(offsets, cursor, bsum);
    scatter_kernel<<<egrid, 256, 0, stream>>>(ei, cursor, csr);

    const int ngrid4 = (N_NODES + 3) / 4;

    // ---- layer 1: es -> aggregate(x) -> per-head GEMM ----
    es1_kernel<<<391, 256, 0, stream>>>(x, W1a, es, ed);
    aggregate1_kernel<<<ngrid4, 256, 0, stream>>>(xb, csr, offsets, es, ed, xab);
    dim3 g1grid(M_PAD / 128, HEADS);
    gemm_h1_kernel<<<g1grid, 256, 0, stream>>>(xab, w1thi, w1tlo, b1, h1b, N_NODES);

    // ---- layer 2: es -> aggregate(h1) -> GEMM ----
    es2_kernel<<<391, 256, 0, stream>>>(h1b, W2a, es, ed);
    aggregate2_kernel<<<ngrid4, 256, 0, stream>>>(h1b, csr, offsets, es, ed, h1ab);
    gemm_h2_kernel<<<M_PAD / 128, 256, 0, stream>>>(h1ab, w2thi, w2tlo, b2, h2b, N_NODES);

    // ---- pooling + MLP ----
    pool_sum_kernel<<<(N_NODES + PRB - 1) / PRB, 640, 0, stream>>>(xb, h1b, h2b, batch, psums);
    mlp_kernel<<<NGRAPH, 256, 0, stream>>>(psums, goff, W3, b3, W4, b4, out);
}

// Round 16
// 438.150 us; speedup vs baseline: 1.2215x; 1.2215x over previous
//
#include <hip/hip_runtime.h>
#include <cstdint>
#include <cstddef>

#define N_NODES 50000
#define M_PAD 50048    // 391 * 128, covers GEMM tile over-read
#define E_EDGES 800000
#define INCH 128
#define HID 64
#define HEADS 4
#define NHD 256      // HEADS*HID
#define NGRAPH 64
#define DCAT 640     // 128 + 256 + 256
#define NEG_SLOPE 0.2f

typedef __attribute__((ext_vector_type(8))) short bf16x8;
typedef __attribute__((ext_vector_type(4))) float f32x4;

// round-to-nearest-even fp32 -> bf16 bits
static __device__ inline unsigned short f2bf(float f) {
    unsigned int u = __float_as_uint(f);
    unsigned int r = (u + 0x7FFFu + ((u >> 16) & 1u)) >> 16;
    return (unsigned short)r;
}
static __device__ inline float bf2f(unsigned short b) {
    return __uint_as_float(((unsigned int)b) << 16);
}

// ---- fused preamble: hist + graph_offsets + psums-zero + hi/lo splits -------
#define W1N (INCH * NHD)            // 32768
#define W2N (NHD * NHD)             // 65536
#define XN  (N_NODES * INCH)        // 6.4M
#define HB  ((E_EDGES + 255) / 256)           // 3125 hist blocks
#define GB  ((N_NODES + 255) / 256)           // 196 graph_offsets blocks
#define PZB ((NGRAPH * DCAT + 255) / 256)     // 160 psums-zero blocks
#define SPB ((W1N + W2N + XN + 255) / 256)    // 25384 split blocks
#define PREPB (HB + GB + PZB + SPB)

__global__ void prep_kernel(
    const int* __restrict__ ei, const int* __restrict__ batch,
    const float* __restrict__ W1, const float* __restrict__ W2,
    const float* __restrict__ x,
    int* __restrict__ counts, int* __restrict__ goff,
    float* __restrict__ psums,
    unsigned short* __restrict__ w1thi, unsigned short* __restrict__ w1tlo,
    unsigned short* __restrict__ w2thi, unsigned short* __restrict__ w2tlo,
    unsigned short* __restrict__ xhi, unsigned short* __restrict__ xlo)
{
    const int b = blockIdx.x;
    if (b < HB) {                               // ---- histogram of dst ----
        const int e = b * 256 + threadIdx.x;
        if (e < E_EDGES) atomicAdd(&counts[ei[E_EDGES + e]], 1);
        return;
    }
    if (b < HB + GB) {                          // ---- graph offsets ----
        const int n = (b - HB) * 256 + threadIdx.x;
        if (n >= N_NODES) return;
        const int bb = batch[n];
        const int bp = (n == 0) ? -1 : batch[n - 1];
        for (int g = bp + 1; g <= bb; ++g) goff[g] = n;
        if (n == N_NODES - 1)
            for (int g = bb + 1; g <= NGRAPH; ++g) goff[g] = N_NODES;
        return;
    }
    if (b < HB + GB + PZB) {                    // ---- zero psums ----
        const int i = (b - HB - GB) * 256 + threadIdx.x;
        if (i < NGRAPH * DCAT) psums[i] = 0.f;
        return;
    }
    // ---- hi/lo splits: W1^T, W2^T, x ----
    const int i = (b - HB - GB - PZB) * 256 + threadIdx.x;
    float v; unsigned short* dhi; unsigned short* dlo; int idx;
    if (i < W1N) {
        const int n = i / INCH, k = i - n * INCH;
        v = W1[(size_t)k * NHD + n]; dhi = w1thi; dlo = w1tlo; idx = i;
    } else if (i < W1N + W2N) {
        const int j = i - W1N;
        const int n = j / NHD, k = j - n * NHD;
        v = W2[(size_t)k * NHD + n]; dhi = w2thi; dlo = w2tlo; idx = j;
    } else {
        const int j = i - W1N - W2N;
        if (j >= XN) return;
        v = x[j]; dhi = xhi; dlo = xlo; idx = j;
    }
    const unsigned short h = f2bf(v);
    dhi[idx] = h;
    dlo[idx] = f2bf(v - bf2f(h));
}

// ------- MFMA GEMM (3-pass): Cb[M,256] = (Ahi+Alo) @ (Bhi+Blo) ---------------
// Full-N tile: A fetched once per GEMM. 4 waves of 64x128; GK=32.
#define GK 32
#define LDA 40   // LDS row stride (80B: b128 reads 2-way aliasing = free)

__global__ __launch_bounds__(256, 2) void gemm_mfma(
    const unsigned short* __restrict__ Athi,
    const unsigned short* __restrict__ Atlo,
    const unsigned short* __restrict__ Bthi,
    const unsigned short* __restrict__ Btlo,
    const float* __restrict__ asrc, const float* __restrict__ adst,
    unsigned short* __restrict__ Cb, float* __restrict__ es,
    float* __restrict__ ed, int M, int K)
{
    __shared__ unsigned short Ahi[128 * LDA];
    __shared__ unsigned short Alo[128 * LDA];
    __shared__ unsigned short Bhi[256 * LDA];
    __shared__ unsigned short Blo[256 * LDA];

    const int t    = threadIdx.x;
    const int row0 = blockIdx.x * 128;
    const int wave = t >> 6, lane = t & 63;
    const int wr  = (wave >> 1) * 64;     // wave row offset (0/64)
    const int wc2 = (wave & 1) * 128;     // wave col offset (0/128)
    const int m16 = lane & 15, quad = lane >> 4;

    f32x4 acc[4][8];
#pragma unroll
    for (int i = 0; i < 4; ++i)
#pragma unroll
        for (int j = 0; j < 8; ++j) acc[i][j] = (f32x4){0.f, 0.f, 0.f, 0.f};

    for (int k0 = 0; k0 < K; k0 += GK) {
#pragma unroll
        for (int i = 0; i < 2; ++i) {
            const int seg = t + i * 256;         // 512 segs of 8 bf16
            const int r = seg >> 2, p = (seg & 3) * 8;
            const size_t ga = (size_t)(row0 + r) * K + k0 + p;
            *(int4*)(&Ahi[r * LDA + p]) = *(const int4*)(Athi + ga);
            *(int4*)(&Alo[r * LDA + p]) = *(const int4*)(Atlo + ga);
        }
#pragma unroll
        for (int i = 0; i < 4; ++i) {
            const int seg = t + i * 256;         // 1024 segs of 8 bf16
            const int r = seg >> 2, p = (seg & 3) * 8;
            const size_t gb = (size_t)r * K + k0 + p;
            *(int4*)(&Bhi[r * LDA + p]) = *(const int4*)(Bthi + gb);
            *(int4*)(&Blo[r * LDA + p]) = *(const int4*)(Btlo + gb);
        }
        __syncthreads();

        bf16x8 afh[4], afl[4];
#pragma unroll
        for (int i = 0; i < 4; ++i) {
            const int r = wr + i * 16 + m16;
            afh[i] = *(const bf16x8*)(&Ahi[r * LDA + quad * 8]);
            afl[i] = *(const bf16x8*)(&Alo[r * LDA + quad * 8]);
        }
#pragma unroll
        for (int j = 0; j < 8; ++j) {
            const int n = wc2 + j * 16 + m16;
            const bf16x8 bh = *(const bf16x8*)(&Bhi[n * LDA + quad * 8]);
            const bf16x8 bl = *(const bf16x8*)(&Blo[n * LDA + quad * 8]);
#pragma unroll
            for (int i = 0; i < 4; ++i) {
                acc[i][j] = __builtin_amdgcn_mfma_f32_16x16x32_bf16(afh[i], bh, acc[i][j], 0, 0, 0);
                acc[i][j] = __builtin_amdgcn_mfma_f32_16x16x32_bf16(afh[i], bl, acc[i][j], 0, 0, 0);
                acc[i][j] = __builtin_amdgcn_mfma_f32_16x16x32_bf16(afl[i], bh, acc[i][j], 0, 0, 0);
            }
        }
        __syncthreads();
    }

    // ---- epilogue 1: bf16 C store (C/D layout col=lane&15, row=quad*4+reg)
#pragma unroll
    for (int i = 0; i < 4; ++i)
#pragma unroll
        for (int reg = 0; reg < 4; ++reg) {
            const int r = row0 + wr + i * 16 + quad * 4 + reg;
            if (r < M) {
#pragma unroll
                for (int j = 0; j < 8; ++j)
                    Cb[(size_t)r * NHD + wc2 + j * 16 + m16] = f2bf(acc[i][j][reg]);
            }
        }

    // ---- epilogue 2: fused attention coefficients, 2 heads per wave ----
    const int hbase = wc2 >> 6;     // heads hbase, hbase+1
    float a_s0[4], a_d0[4], a_s1[4], a_d1[4];
#pragma unroll
    for (int j = 0; j < 4; ++j) {
        a_s0[j] = asrc[hbase * HID + j * 16 + m16];
        a_d0[j] = adst[hbase * HID + j * 16 + m16];
        a_s1[j] = asrc[(hbase + 1) * HID + j * 16 + m16];
        a_d1[j] = adst[(hbase + 1) * HID + j * 16 + m16];
    }
#pragma unroll
    for (int i = 0; i < 4; ++i)
#pragma unroll
        for (int reg = 0; reg < 4; ++reg) {
            float ps0 = 0.f, pd0 = 0.f, ps1 = 0.f, pd1 = 0.f;
#pragma unroll
            for (int j = 0; j < 4; ++j) {
                const float v0 = acc[i][j][reg];
                const float v1 = acc[i][j + 4][reg];
                ps0 += v0 * a_s0[j];
                pd0 += v0 * a_d0[j];
                ps1 += v1 * a_s1[j];
                pd1 += v1 * a_d1[j];
            }
#pragma unroll
            for (int off = 1; off < 16; off <<= 1) {
                ps0 += __shfl_xor(ps0, off, 64);
                pd0 += __shfl_xor(pd0, off, 64);
                ps1 += __shfl_xor(ps1, off, 64);
                pd1 += __shfl_xor(pd1, off, 64);
            }
            if (m16 == 0) {
                const int r = row0 + wr + i * 16 + quad * 4 + reg;
                if (r < M) {
                    es[r * HEADS + hbase]     = ps0;
                    ed[r * HEADS + hbase]     = pd0;
                    es[r * HEADS + hbase + 1] = ps1;
                    ed[r * HEADS + hbase + 1] = pd1;
                }
            }
        }
}

// ------- MFMA GEMM v2 (2-pass): Cb[M,256] = A(bf16) @ (Bhi+Blo) --------------
// Layer-2 variant: A is plain bf16. LB(256,2): no VGPR spill (R13's (256,3)
// capped VGPRs at ~170 < 180 needed -> scratch spill, +20us).
__global__ __launch_bounds__(256, 2) void gemm_mfma2(
    const unsigned short* __restrict__ At,
    const unsigned short* __restrict__ Bthi,
    const unsigned short* __restrict__ Btlo,
    const float* __restrict__ asrc, const float* __restrict__ adst,
    unsigned short* __restrict__ Cb, float* __restrict__ es,
    float* __restrict__ ed, int M, int K)
{
    __shared__ unsigned short Ash[128 * LDA];
    __shared__ unsigned short Bhi[256 * LDA];
    __shared__ unsigned short Blo[256 * LDA];

    const int t    = threadIdx.x;
    const int row0 = blockIdx.x * 128;
    const int wave = t >> 6, lane = t & 63;
    const int wr  = (wave >> 1) * 64;
    const int wc2 = (wave & 1) * 128;
    const int m16 = lane & 15, quad = lane >> 4;

    f32x4 acc[4][8];
#pragma unroll
    for (int i = 0; i < 4; ++i)
#pragma unroll
        for (int j = 0; j < 8; ++j) acc[i][j] = (f32x4){0.f, 0.f, 0.f, 0.f};

    for (int k0 = 0; k0 < K; k0 += GK) {
#pragma unroll
        for (int i = 0; i < 2; ++i) {
            const int seg = t + i * 256;         // 512 segs of 8 bf16
            const int r = seg >> 2, p = (seg & 3) * 8;
            *(int4*)(&Ash[r * LDA + p]) = *(const int4*)(At + (size_t)(row0 + r) * K + k0 + p);
        }
#pragma unroll
        for (int i = 0; i < 4; ++i) {
            const int seg = t + i * 256;         // 1024 segs of 8 bf16
            const int r = seg >> 2, p = (seg & 3) * 8;
            const size_t gb = (size_t)r * K + k0 + p;
            *(int4*)(&Bhi[r * LDA + p]) = *(const int4*)(Bthi + gb);
            *(int4*)(&Blo[r * LDA + p]) = *(const int4*)(Btlo + gb);
        }
        __syncthreads();

        bf16x8 af[4];
#pragma unroll
        for (int i = 0; i < 4; ++i) {
            const int r = wr + i * 16 + m16;
            af[i] = *(const bf16x8*)(&Ash[r * LDA + quad * 8]);
        }
#pragma unroll
        for (int j = 0; j < 8; ++j) {
            const int n = wc2 + j * 16 + m16;
            const bf16x8 bh = *(const bf16x8*)(&Bhi[n * LDA + quad * 8]);
            const bf16x8 bl = *(const bf16x8*)(&Blo[n * LDA + quad * 8]);
#pragma unroll
            for (int i = 0; i < 4; ++i) {
                acc[i][j] = __builtin_amdgcn_mfma_f32_16x16x32_bf16(af[i], bh, acc[i][j], 0, 0, 0);
                acc[i][j] = __builtin_amdgcn_mfma_f32_16x16x32_bf16(af[i], bl, acc[i][j], 0, 0, 0);
            }
        }
        __syncthreads();
    }

#pragma unroll
    for (int i = 0; i < 4; ++i)
#pragma unroll
        for (int reg = 0; reg < 4; ++reg) {
            const int r = row0 + wr + i * 16 + quad * 4 + reg;
            if (r < M) {
#pragma unroll
                for (int j = 0; j < 8; ++j)
                    Cb[(size_t)r * NHD + wc2 + j * 16 + m16] = f2bf(acc[i][j][reg]);
            }
        }

    const int hbase = wc2 >> 6;
    float a_s0[4], a_d0[4], a_s1[4], a_d1[4];
#pragma unroll
    for (int j = 0; j < 4; ++j) {
        a_s0[j] = asrc[hbase * HID + j * 16 + m16];
        a_d0[j] = adst[hbase * HID + j * 16 + m16];
        a_s1[j] = asrc[(hbase + 1) * HID + j * 16 + m16];
        a_d1[j] = adst[(hbase + 1) * HID + j * 16 + m16];
    }
#pragma unroll
    for (int i = 0; i < 4; ++i)
#pragma unroll
        for (int reg = 0; reg < 4; ++reg) {
            float ps0 = 0.f, pd0 = 0.f, ps1 = 0.f, pd1 = 0.f;
#pragma unroll
            for (int j = 0; j < 4; ++j) {
                const float v0 = acc[i][j][reg];
                const float v1 = acc[i][j + 4][reg];
                ps0 += v0 * a_s0[j];
                pd0 += v0 * a_d0[j];
                ps1 += v1 * a_s1[j];
                pd1 += v1 * a_d1[j];
            }
#pragma unroll
            for (int off = 1; off < 16; off <<= 1) {
                ps0 += __shfl_xor(ps0, off, 64);
                pd0 += __shfl_xor(pd0, off, 64);
                ps1 += __shfl_xor(ps1, off, 64);
                pd1 += __shfl_xor(pd1, off, 64);
            }
            if (m16 == 0) {
                const int r = row0 + wr + i * 16 + quad * 4 + reg;
                if (r < M) {
                    es[r * HEADS + hbase]     = ps0;
                    ed[r * HEADS + hbase]     = pd0;
                    es[r * HEADS + hbase + 1] = ps1;
                    ed[r * HEADS + hbase + 1] = pd1;
                }
            }
        }
}

// ------------------------------ CSR scan ------------------------------------
#define SBLK 1024
#define NSCB ((N_NODES + SBLK - 1) / SBLK)   // 49

__global__ __launch_bounds__(1024) void scan_local_kernel(
    const int* __restrict__ counts, int* __restrict__ offsets,
    int* __restrict__ bsum)
{
    __shared__ int tmp[SBLK];
    const int t = threadIdx.x;
    const int i = blockIdx.x * SBLK + t;
    const int v = (i < N_NODES) ? counts[i] : 0;
    tmp[t] = v;
    __syncthreads();
    for (int off = 1; off < SBLK; off <<= 1) {
        const int u = (t >= off) ? tmp[t - off] : 0;
        __syncthreads();
        tmp[t] += u;
        __syncthreads();
    }
    if (i < N_NODES) offsets[i] = tmp[t] - v;    // local exclusive prefix
    if (t == SBLK - 1) bsum[blockIdx.x] = tmp[t];
}

__global__ __launch_bounds__(1024) void scan_final_kernel(
    int* __restrict__ offsets, int* __restrict__ cursor,
    const int* __restrict__ bsum)
{
    __shared__ int base_sh;
    const int b = blockIdx.x;
    if (threadIdx.x == 0) {
        int s = 0;
        for (int j = 0; j < b; ++j) s += bsum[j];
        base_sh = s;
    }
    __syncthreads();
    const int i = b * SBLK + threadIdx.x;
    if (i < N_NODES) {
        const int v = offsets[i] + base_sh;
        offsets[i] = v;
        cursor[i]  = v;
    }
    if (b == 0 && threadIdx.x == 0) offsets[N_NODES] = E_EDGES;
}

// scatter: csr holds the SRC node id directly
__global__ void scatter_kernel(const int* __restrict__ ei, int* __restrict__ cursor,
                               int* __restrict__ csr)
{
    const int e = blockIdx.x * 256 + threadIdx.x;
    if (e >= E_EDGES) return;
    const int s = ei[e];
    const int d = ei[E_EDGES + e];
    const int pos = atomicAdd(&cursor[d], 1);
    csr[pos] = s;
}

// ------- fused softmax + aggregation: one wave per dst node ------------------
__global__ __launch_bounds__(256) void aggregate_fused(
    const unsigned short* __restrict__ hb, const int* __restrict__ csr,
    const int* __restrict__ offsets,
    const float* __restrict__ es, const float* __restrict__ ed,
    const float* __restrict__ bias, unsigned short* __restrict__ outhi)
{
    const int wid  = threadIdx.x >> 6;
    const int lane = threadIdx.x & 63;
    const int node = blockIdx.x * 4 + wid;
    if (node >= N_NODES) return;
    const int head = lane >> 4;          // col = lane*4 -> head = col/64
    const int col  = lane * 4;
    const int sub  = lane & 15;          // edge slot within 16-edge chunk

    const float edc = ed[node * 4 + head];
    const int beg = offsets[node], end = offsets[node + 1];

    float4 acc = make_float4(0.f, 0.f, 0.f, 0.f);
    float dsum = 0.f;

    int base = beg;
    int m_cur = min(16, end - base);
    int s_cur = 0; float w_cur = 0.f;
    if (base < end && sub < m_cur) {
        s_cur = csr[base + sub];
        float u = es[s_cur * 4 + head] + edc;
        u = u > 0.f ? u : NEG_SLOPE * u;
        w_cur = expf(u);
    }

    while (base < end) {
        const int base_n = base + 16;
        const int m_nxt = min(16, end - base_n);
        int s_nxt = 0; float w_nxt = 0.f;
        if (base_n < end && sub < m_nxt) {
            s_nxt = csr[base_n + sub];
            float u = es[s_nxt * 4 + head] + edc;
            u = u > 0.f ? u : NEG_SLOPE * u;
            w_nxt = expf(u);
        }
        if (m_cur == 16) {
#pragma unroll
            for (int i = 0; i < 16; ++i) {
                const int   s = (int)__builtin_amdgcn_readlane((unsigned)s_cur, i);
                const float w = __shfl(w_cur, (lane & 48) + i, 64);
                const ushort4 v = *(const ushort4*)(hb + (size_t)s * NHD + col);
                acc.x += w * bf2f(v.x);
                acc.y += w * bf2f(v.y);
                acc.z += w * bf2f(v.z);
                acc.w += w * bf2f(v.w);
                dsum += w;
            }
        } else {
            for (int i = 0; i < m_cur; ++i) {
                const int   s = __shfl(s_cur, i, 64);
                const float w = __shfl(w_cur, (lane & 48) + i, 64);
                const ushort4 v = *(const ushort4*)(hb + (size_t)s * NHD + col);
                acc.x += w * bf2f(v.x);
                acc.y += w * bf2f(v.y);
                acc.z += w * bf2f(v.z);
                acc.w += w * bf2f(v.w);
                dsum += w;
            }
        }
        s_cur = s_nxt; w_cur = w_nxt; m_cur = m_nxt; base = base_n;
    }

    const float inv = 1.0f / (dsum + 1e-16f);
    const float4 bb = *(const float4*)(bias + col);
    float4 o;
    o.x = fmaxf(acc.x * inv + bb.x, 0.f);
    o.y = fmaxf(acc.y * inv + bb.y, 0.f);
    o.z = fmaxf(acc.z * inv + bb.z, 0.f);
    o.w = fmaxf(acc.w * inv + bb.w, 0.f);
    ushort4 oh;
    oh.x = f2bf(o.x); oh.y = f2bf(o.y); oh.z = f2bf(o.z); oh.w = f2bf(o.w);
    *(ushort4*)(outhi + (size_t)node * NHD + col) = oh;
}

// ------------------------------ pooling (all-bf16 sources) -------------------
#define PRB 128

__global__ __launch_bounds__(640) void pool_sum_kernel(
    const unsigned short* __restrict__ xhi, const unsigned short* __restrict__ h1b,
    const unsigned short* __restrict__ h2b, const int* __restrict__ batch,
    float* __restrict__ sums)
{
    __shared__ int bsh[PRB];
    const int c  = threadIdx.x;            // 0..639
    const int r0 = blockIdx.x * PRB;
    const int r1 = min(N_NODES, r0 + PRB);
    const int nr = r1 - r0;
    if (c < nr) bsh[c] = batch[r0 + c];
    __syncthreads();

    const unsigned short* srcb; int ld, cc;
    if (c < INCH)            { srcb = xhi; ld = INCH; cc = c; }
    else if (c < INCH + NHD) { srcb = h1b; ld = NHD;  cc = c - INCH; }
    else                     { srcb = h2b; ld = NHD;  cc = c - INCH - NHD; }

    float sum = 0.f;
    int g = bsh[0];
    for (int i = 0; i < nr; ++i) {
        const int gb = bsh[i];
        if (gb != g) {
            atomicAdd(&sums[g * DCAT + c], sum);
            sum = 0.f;
            g = gb;
        }
        sum += bf2f(srcb[(size_t)(r0 + i) * ld + cc]);
    }
    atomicAdd(&sums[g * DCAT + c], sum);
}

// --------------- MLP head: one graph per block (64 blocks) -------------------
__global__ __launch_bounds__(256) void mlp_kernel(
    const float* __restrict__ psums, const int* __restrict__ goff,
    const float* __restrict__ W3, const float* __restrict__ b3,
    const float* __restrict__ W4, const float* __restrict__ b4,
    float* __restrict__ out)
{
    const int g = blockIdx.x;
    __shared__ float p[DCAT];
    __shared__ float hm[256];
    const float inv = 1.0f / fmaxf((float)(goff[g + 1] - goff[g]), 1.0f);
    for (int i = threadIdx.x; i < DCAT; i += 256)
        p[i] = psums[(size_t)g * DCAT + i] * inv;
    __syncthreads();
    const int c = threadIdx.x;
    float s = b3[c];
    for (int k = 0; k < DCAT; ++k) s += p[k] * W3[(size_t)k * 256 + c];
    hm[c] = fmaxf(s, 0.f);
    __syncthreads();
    if (c < 128) {
        float o = b4[c];
        for (int k = 0; k < 256; ++k) o += hm[k] * W4[(size_t)k * 128 + c];
        out[(size_t)g * 128 + c] = o;
    }
}

// ------------------------------ launch --------------------------------------
extern "C" void kernel_launch(void* const* d_in, const int* in_sizes, int n_in,
                              void* d_out, int out_size, void* d_ws, size_t ws_size,
                              hipStream_t stream)
{
    const float* x     = (const float*)d_in[0];
    const int*   ei    = (const int*)d_in[1];
    const int*   batch = (const int*)d_in[2];
    const float* W1    = (const float*)d_in[3];
    const float* a1s   = (const float*)d_in[4];
    const float* a1d   = (const float*)d_in[5];
    const float* b1    = (const float*)d_in[6];
    const float* W2    = (const float*)d_in[7];
    const float* a2s   = (const float*)d_in[8];
    const float* a2d   = (const float*)d_in[9];
    const float* b2    = (const float*)d_in[10];
    const float* W3    = (const float*)d_in[11];
    const float* b3    = (const float*)d_in[12];
    const float* W4    = (const float*)d_in[13];
    const float* b4    = (const float*)d_in[14];
    float* out = (float*)d_out;

    // workspace carve
    size_t off = 0;
    auto carve = [&](size_t bytes) -> void* {
        void* p = (char*)d_ws + off;
        off = (off + bytes + 255) & ~(size_t)255;
        return p;
    };
    unsigned short* xhi   = (unsigned short*)carve((size_t)M_PAD * INCH * 2);
    unsigned short* xlo   = (unsigned short*)carve((size_t)M_PAD * INCH * 2);
    unsigned short* ghi   = (unsigned short*)carve((size_t)N_NODES * NHD * 2);  // GEMM out (gather src)
    unsigned short* h1hi  = (unsigned short*)carve((size_t)M_PAD * NHD * 2);
    unsigned short* h2hi  = (unsigned short*)carve((size_t)N_NODES * NHD * 2);
    float* es     = (float*)carve((size_t)N_NODES * HEADS * 4);
    float* ed     = (float*)carve((size_t)N_NODES * HEADS * 4);
    float* psums  = (float*)carve((size_t)NGRAPH * DCAT * 4);
    int*   counts  = (int*)carve((size_t)N_NODES * 4);
    int*   offsets = (int*)carve((size_t)(N_NODES + 1) * 4);
    int*   cursor  = (int*)carve((size_t)N_NODES * 4);
    int*   csr     = (int*)carve((size_t)E_EDGES * 4);
    int*   goff    = (int*)carve((size_t)(NGRAPH + 1) * 4);
    int*   bsum    = (int*)carve((size_t)NSCB * 4);
    unsigned short* w1thi = (unsigned short*)carve((size_t)NHD * INCH * 2);
    unsigned short* w1tlo = (unsigned short*)carve((size_t)NHD * INCH * 2);
    unsigned short* w2thi = (unsigned short*)carve((size_t)NHD * NHD * 2);
    unsigned short* w2tlo = (unsigned short*)carve((size_t)NHD * NHD * 2);

    const int egrid = (E_EDGES + 255) / 256;

    // ---- preamble: histogram + graph offsets + psums zero + splits ----
    hipMemsetAsync(counts, 0, (size_t)N_NODES * 4, stream);
    prep_kernel<<<PREPB, 256, 0, stream>>>(ei, batch, W1, W2, x,
                                           counts, goff, psums,
                                           w1thi, w1tlo, w2thi, w2tlo, xhi, xlo);
    scan_local_kernel<<<NSCB, SBLK, 0, stream>>>(counts, offsets, bsum);
    scan_final_kernel<<<NSCB, SBLK, 0, stream>>>(offsets, cursor, bsum);
    scatter_kernel<<<egrid, 256, 0, stream>>>(ei, cursor, csr);

    const int ggrid = M_PAD / 128;   // 391, full-N tile

    // ---- layer 1 (3-pass GEMM: x at full fp32 precision) ----
    gemm_mfma<<<ggrid, 256, 0, stream>>>(xhi, xlo, w1thi, w1tlo, a1s, a1d,
                                         ghi, es, ed, N_NODES, INCH);
    aggregate_fused<<<(N_NODES + 3) / 4, 256, 0, stream>>>(ghi, csr, offsets,
                                                           es, ed, b1, h1hi);
    // ---- layer 2 (2-pass GEMM: h1 as plain bf16) ----
    gemm_mfma2<<<ggrid, 256, 0, stream>>>(h1hi, w2thi, w2tlo, a2s, a2d,
                                          ghi, es, ed, N_NODES, NHD);
    aggregate_fused<<<(N_NODES + 3) / 4, 256, 0, stream>>>(ghi, csr, offsets,
                                                           es, ed, b2, h2hi);

    // ---- pooling + MLP ----
    pool_sum_kernel<<<(N_NODES + PRB - 1) / PRB, 640, 0, stream>>>(xhi, h1hi, h2hi, batch, psums);
    mlp_kernel<<<NGRAPH, 256, 0, stream>>>(psums, goff, W3, b3, W4, b4, out);
}